// Round 8
// baseline (149.883 us; speedup 1.0000x reference)
//
#include <hip/hip_runtime.h>

// Problem constants (reference: N=32768, M=8192, D=64, fp32)
#define N_ROWS 32768
#define M_COLS 8192
#define D_DIM  64
#define JC     8                      // j-chunks (grid.y) -> partial mins
#define BLOCK  256
#define GROUPS 8                      // 16-row groups per wave -> 128 rows/wave
#define ROWS_PER_BLOCK 512            // 4 waves x 128 rows
#define CHUNK  (M_COLS / JC)          // 1024 j per chunk
#define TJ     64                     // j per per-wave LDS tile (64 x 128 B = 8 KB)
#define NTILE  (CHUNK / TJ)           // 16 tiles per chunk

typedef _Float16 v8h __attribute__((ext_vector_type(8)));
typedef _Float16 v4h __attribute__((ext_vector_type(4)));
typedef float    v4f __attribute__((ext_vector_type(4)));

// ---------- kernel 1: yh = (half)y, th[j] = (psi[j]-||y_j||^2)/2; zero out+done ----------
__global__ __launch_bounds__(BLOCK) void prep_kernel(
    const float* __restrict__ y, const float* __restrict__ psi,
    _Float16* __restrict__ yh, float* __restrict__ th,
    float* __restrict__ out, int* __restrict__ done) {
    const int tid = threadIdx.x;
    if (blockIdx.x == 0) {            // zero accumulator + completion counters
        if (tid < 64) done[tid] = 0;
        else if (tid == 64) out[0] = 0.f;
    }
    const int j = blockIdx.x * 16 + (tid >> 4);  // y row
    const int n = tid & 15;                      // 4-elem segment
    const float4 v = *(const float4*)(y + (size_t)j * D_DIM + n * 4);
    float s = v.x * v.x + v.y * v.y + v.z * v.z + v.w * v.w;
    v4h hv = { (_Float16)v.x, (_Float16)v.y, (_Float16)v.z, (_Float16)v.w };
    *(v4h*)(yh + (size_t)j * D_DIM + n * 4) = hv;
#pragma unroll
    for (int m = 1; m < 16; m <<= 1) s += __shfl_xor(s, m, 64);
    if (n == 0) th[j] = 0.5f * (psi[j] - s);
}

// ---------- kernel 2: MFMA partial min + fused final reduce ----------
// part[jc*N + i] = min_{j in chunk}(t[j] - 2<x_i,y_j>) = -2 max_j(<x_i,y_j>+th[j])
// Per-wave PRIVATE double-buffered LDS tiles, NO __syncthreads in the K-loop:
// issue prefetch(t+1) -> compute(t) -> s_waitcnt(0). Last block per row-range
// (device-scope counter) folds min/x^2/psi into out.
__global__ __launch_bounds__(BLOCK) void partial_min_kernel(
    const float* __restrict__ x, const _Float16* __restrict__ yh,
    const float* __restrict__ th, const float* __restrict__ psi,
    float* __restrict__ part, int* __restrict__ done, float* __restrict__ out) {
    __shared__ __align__(16) _Float16 sY[4][2][TJ * D_DIM];  // 4 waves x 2 x 8 KB
    __shared__ __align__(16) float    sTh[4][2][TJ];         // 4 waves x 2 x 256 B

    const int tid  = threadIdx.x;
    const int lane = tid & 63, wave = tid >> 6;
    const int q = lane >> 4, n = lane & 15;
    const int rb    = blockIdx.x;            // row block [0,64)
    const int jc    = blockIdx.y;            // j chunk  [0,8)
    const int jbase = jc * CHUNK;
    const int i_wave = rb * ROWS_PER_BLOCK + wave * 128;

    // A-frags: 8 row-groups x 2 k-chunks, loaded once from fp32 x, cvt to f16.
    v8h a[GROUPS][2];
#pragma unroll
    for (int g = 0; g < GROUPS; ++g) {
        const float* px = x + (size_t)(i_wave + g * 16 + n) * D_DIM + q * 8;
#pragma unroll
        for (int c = 0; c < 2; ++c) {
            float4 f0 = *(const float4*)(px + c * 32);
            float4 f1 = *(const float4*)(px + c * 32 + 4);
            v8h av = { (_Float16)f0.x, (_Float16)f0.y, (_Float16)f0.z, (_Float16)f0.w,
                       (_Float16)f1.x, (_Float16)f1.y, (_Float16)f1.z, (_Float16)f1.w };
            a[g][c] = av;
        }
    }

    float maxs[GROUPS][4];
#pragma unroll
    for (int g = 0; g < GROUPS; ++g)
#pragma unroll
        for (int r = 0; r < 4; ++r) maxs[g][r] = -INFINITY;

    // ---- per-wave async stage of tile t into this wave's buffer b ----
    // LDS 16B-slot sIdx holds (row = sIdx/8, chunk = (sIdx%8) ^ (row&7)); same
    // XOR swizzle as R6/R7 (measured 0 bank conflicts).
    auto stage = [&](int t, int b) {
#pragma unroll
        for (int k = 0; k < 8; ++k) {
            const int sIdx = k * 64 + lane;              // [0,512) 16B units
            const int row  = sIdx >> 3;
            const int c    = (sIdx & 7) ^ (row & 7);
            const _Float16* g = yh + (size_t)(jbase + t * TJ + row) * D_DIM + c * 8;
            __builtin_amdgcn_global_load_lds(
                (const __attribute__((address_space(1))) void*)g,
                (__attribute__((address_space(3))) void*)(&sY[wave][b][(size_t)k * 512]),
                16, 0, 0);
        }
        if (lane < 16) {  // th tile: 64 floats = 256 B
            const float* gt_ = th + jbase + t * TJ + lane * 4;
            __builtin_amdgcn_global_load_lds(
                (const __attribute__((address_space(1))) void*)gt_,
                (__attribute__((address_space(3))) void*)(&sTh[wave][b][0]),
                16, 0, 0);
        }
    };

    stage(0, 0);
    __builtin_amdgcn_s_waitcnt(0);     // tile 0 (and A-frags) resident
    __builtin_amdgcn_sched_barrier(0);

    const int sl0 = q ^ (n & 7);       // swizzled slot for chunk q of row (..8k+n)

#pragma unroll 1
    for (int t = 0; t < NTILE; ++t) {
        const int cur = t & 1;
        if (t + 1 < NTILE) stage(t + 1, cur ^ 1);  // prefetch under compute

        const _Float16* buf = &sY[wave][cur][0];
        const float*   tbuf = &sTh[wave][cur][0];
#pragma unroll
        for (int ss = 0; ss < TJ / 16; ++ss) {
            const v8h b0 = *(const v8h*)(buf + (ss * 16 + n) * 64 + sl0 * 8);
            const v8h b1 = *(const v8h*)(buf + (ss * 16 + n) * 64 + (sl0 ^ 4) * 8);
            const float tv = tbuf[ss * 16 + n];
            const v4f tv4 = { tv, tv, tv, tv };   // th[j] rides in the C operand
#pragma unroll
            for (int g = 0; g < GROUPS; ++g) {
                v4f acc = __builtin_amdgcn_mfma_f32_16x16x32_f16(a[g][0], b0, tv4, 0, 0, 0);
                acc     = __builtin_amdgcn_mfma_f32_16x16x32_f16(a[g][1], b1, acc, 0, 0, 0);
#pragma unroll
                for (int r = 0; r < 4; ++r)
                    maxs[g][r] = fmaxf(maxs[g][r], acc[r]);
            }
        }
        // drain this wave's prefetch; placed AFTER compute so latency is hidden
        __builtin_amdgcn_s_waitcnt(0);
        __builtin_amdgcn_sched_barrier(0);
    }

    // reduce max across the 16 j-phase lanes (lane bits 0..3), store -2*max
#pragma unroll
    for (int g = 0; g < GROUPS; ++g) {
#pragma unroll
        for (int r = 0; r < 4; ++r) {
            float v = maxs[g][r];
#pragma unroll
            for (int m = 1; m < 16; m <<= 1)
                v = fmaxf(v, __shfl_xor(v, m, 64));
            if (n == 0)
                part[(size_t)jc * N_ROWS + i_wave + g * 16 + q * 4 + r] = -2.f * v;
        }
    }

    // ---- last block per row-range finishes the reduction ----
    __shared__ int isLast;
    __threadfence();                               // release part[] stores
    if (tid == 0) isLast = (atomicAdd(&done[rb], 1) == JC - 1);
    __syncthreads();
    if (!isLast) return;
    __threadfence();                               // acquire other blocks' part[]

    float s = 0.f;
#pragma unroll
    for (int rr = 0; rr < 2; ++rr) {
        const int i = rb * ROWS_PER_BLOCK + rr * 256 + tid;
        float m = part[i];
#pragma unroll
        for (int c = 1; c < JC; ++c)
            m = fminf(m, part[(size_t)c * N_ROWS + i]);
        const float4* px = (const float4*)(x + (size_t)i * D_DIM);
        float x2 = 0.f;
#pragma unroll
        for (int k = 0; k < D_DIM / 4; ++k) {
            float4 v = px[k];
            x2 += v.x * v.x + v.y * v.y + v.z * v.z + v.w * v.w;
        }
        s += m + x2;
    }
    s *= (1.f / (float)N_ROWS);
    if (tid < CHUNK / JC)  // this rb's 128-element psi slice (64 blocks x 128 = 8192)
        s += psi[rb * 128 + tid] * (1.f / (float)M_COLS);
    for (int off = 32; off > 0; off >>= 1) s += __shfl_down(s, off, 64);
    __shared__ float red[4];
    if (lane == 0) red[wave] = s;
    __syncthreads();
    if (tid == 0) atomicAdd(out, red[0] + red[1] + red[2] + red[3]);
}

extern "C" void kernel_launch(void* const* d_in, const int* in_sizes, int n_in,
                              void* d_out, int out_size, void* d_ws, size_t ws_size,
                              hipStream_t stream) {
    const float* x   = (const float*)d_in[0];   // [N,D]
    const float* y   = (const float*)d_in[1];   // [M,D]
    const float* psi = (const float*)d_in[2];   // [M]
    float* out = (float*)d_out;

    // workspace layout
    float* part = (float*)d_ws;                       // JC*N floats = 1 MB
    float* th   = part + (size_t)JC * N_ROWS;         // M floats
    _Float16* yh = (_Float16*)(th + M_COLS);          // M*D halves = 1 MB (16B-aligned)
    int* done = (int*)(yh + (size_t)M_COLS * D_DIM);  // 64 counters

    prep_kernel<<<M_COLS / 16, BLOCK, 0, stream>>>(y, psi, yh, th, out, done);
    partial_min_kernel<<<dim3(N_ROWS / ROWS_PER_BLOCK, JC), BLOCK, 0, stream>>>(
        x, yh, th, psi, part, done, out);
}

// Round 9
// 114.513 us; speedup vs baseline: 1.3089x; 1.3089x over previous
//
#include <hip/hip_runtime.h>

// Problem constants (reference: N=32768, M=8192, D=64, fp32)
#define N_ROWS 32768
#define M_COLS 8192
#define D_DIM  64
#define JC     16                     // j-chunks (grid.y); 64x16=1024 blocks = 4/CU
#define BLOCK  256
#define GROUPS 8                      // 16-row groups per wave -> 128 rows/wave
#define ROWS_PER_BLOCK 512            // 4 waves x 128 rows
#define CHUNK  (M_COLS / JC)          // 512 j per chunk
#define TJ     128                    // j per LDS tile (128 rows x 128 B = 16 KB)
#define NTILE  (CHUNK / TJ)           // 4 tiles per chunk

typedef _Float16 v8h __attribute__((ext_vector_type(8)));
typedef _Float16 v4h __attribute__((ext_vector_type(4)));
typedef float    v4f __attribute__((ext_vector_type(4)));

// ---------- kernel 1: yh = (half)y, th[j] = (psi[j] - ||y_j||^2)/2; zero out ----------
__global__ __launch_bounds__(BLOCK) void prep_kernel(
    const float* __restrict__ y, const float* __restrict__ psi,
    _Float16* __restrict__ yh, float* __restrict__ th, float* __restrict__ out) {
    const int tid = threadIdx.x;
    if (blockIdx.x == 0 && tid == 0) out[0] = 0.f;   // atomic accumulator init
    const int j = blockIdx.x * 16 + (tid >> 4);  // y row
    const int n = tid & 15;                      // 4-elem segment
    const float4 v = *(const float4*)(y + (size_t)j * D_DIM + n * 4);
    float s = v.x * v.x + v.y * v.y + v.z * v.z + v.w * v.w;
    v4h hv = { (_Float16)v.x, (_Float16)v.y, (_Float16)v.z, (_Float16)v.w };
    *(v4h*)(yh + (size_t)j * D_DIM + n * 4) = hv;
#pragma unroll
    for (int m = 1; m < 16; m <<= 1) s += __shfl_xor(s, m, 64);
    if (n == 0) th[j] = 0.5f * (psi[j] - s);
}

// ---------- kernel 2: MFMA partial min over a j-chunk (R7 structure, JC=16) ----------
// part[jc*N + i] = min_{j in chunk} (t[j] - 2<x_i,y_j>) = -2 max_j(<x_i,y_j>+th[j])
// B + th staged global->LDS (async, double-buffered, XOR-swizzled); A in regs.
__global__ __launch_bounds__(BLOCK) void partial_min_kernel(
    const float* __restrict__ x, const _Float16* __restrict__ yh,
    const float* __restrict__ th, float* __restrict__ part) {
    __shared__ __align__(16) _Float16 sY[2][TJ * D_DIM];  // 2 x 16 KB
    __shared__ __align__(16) float    sTh[2][TJ];         // 2 x 512 B

    const int tid  = threadIdx.x;
    const int lane = tid & 63, wave = tid >> 6;
    const int q = lane >> 4, n = lane & 15;
    const int jc    = blockIdx.y;
    const int jbase = jc * CHUNK;
    const int i_wave = blockIdx.x * ROWS_PER_BLOCK + wave * 128;

    // A-frags: 8 row-groups x 2 k-chunks, loaded once from fp32 x, cvt to f16.
    v8h a[GROUPS][2];
#pragma unroll
    for (int g = 0; g < GROUPS; ++g) {
        const float* px = x + (size_t)(i_wave + g * 16 + n) * D_DIM + q * 8;
#pragma unroll
        for (int c = 0; c < 2; ++c) {
            float4 f0 = *(const float4*)(px + c * 32);
            float4 f1 = *(const float4*)(px + c * 32 + 4);
            v8h av = { (_Float16)f0.x, (_Float16)f0.y, (_Float16)f0.z, (_Float16)f0.w,
                       (_Float16)f1.x, (_Float16)f1.y, (_Float16)f1.z, (_Float16)f1.w };
            a[g][c] = av;
        }
    }

    float maxs[GROUPS][4];
#pragma unroll
    for (int g = 0; g < GROUPS; ++g)
#pragma unroll
        for (int r = 0; r < 4; ++r) maxs[g][r] = -INFINITY;

    // ---- async stage of tile t into buffer b (XOR-swizzled on the GLOBAL side) ----
    // LDS 16B-slot sIdx holds (row = sIdx/8, chunk = (sIdx%8) ^ (row&7)).
    auto stage = [&](int t, int b) {
#pragma unroll
        for (int k = 0; k < 4; ++k) {
            const int sIdx = (k * 4 + wave) * 64 + lane;     // [0,1024)
            const int row  = sIdx >> 3;
            const int c    = (sIdx & 7) ^ (row & 7);
            const _Float16* g = yh + (size_t)(jbase + t * TJ + row) * D_DIM + c * 8;
            __builtin_amdgcn_global_load_lds(
                (const __attribute__((address_space(1))) void*)g,
                (__attribute__((address_space(3))) void*)(&sY[b][(size_t)(k * 4 + wave) * 512]),
                16, 0, 0);
        }
        // th tile: 128 floats = 512 B via wave 0, lanes 0-31 (lane*16B dest)
        if (wave == 0 && lane < 32) {
            const float* gt_ = th + jbase + t * TJ + lane * 4;
            __builtin_amdgcn_global_load_lds(
                (const __attribute__((address_space(1))) void*)gt_,
                (__attribute__((address_space(3))) void*)(&sTh[b][0]),
                16, 0, 0);
        }
    };

    stage(0, 0);
    __syncthreads();  // drains vmcnt(0): tile 0 resident

    const int sl0 = q ^ (n & 7);  // swizzled slot for chunk q of row (..8k+n)

    for (int t = 0; t < NTILE; ++t) {
        const int cur = t & 1;
        if (t + 1 < NTILE) stage(t + 1, cur ^ 1);  // prefetch under compute

        const _Float16* buf = &sY[cur][0];
        const float* tbuf = &sTh[cur][0];
#pragma unroll 4
        for (int ss = 0; ss < TJ / 16; ++ss) {
            // row in tile = ss*16+n (row&7 == n&7); chunk q at slot sl0, q+4 at sl0^4
            const v8h b0 = *(const v8h*)(buf + (ss * 16 + n) * 64 + sl0 * 8);
            const v8h b1 = *(const v8h*)(buf + (ss * 16 + n) * 64 + (sl0 ^ 4) * 8);
            const float tv = tbuf[ss * 16 + n];
            const v4f tv4 = { tv, tv, tv, tv };   // th[j] rides in the C operand
#pragma unroll
            for (int g = 0; g < GROUPS; ++g) {
                v4f acc = __builtin_amdgcn_mfma_f32_16x16x32_f16(a[g][0], b0, tv4, 0, 0, 0);
                acc     = __builtin_amdgcn_mfma_f32_16x16x32_f16(a[g][1], b1, acc, 0, 0, 0);
#pragma unroll
                for (int r = 0; r < 4; ++r)
                    maxs[g][r] = fmaxf(maxs[g][r], acc[r]);
            }
        }
        __syncthreads();  // all waves done reading buf `cur`; prefetch drained
    }

    // reduce max across the 16 j-phase lanes (lane bits 0..3), store -2*max
#pragma unroll
    for (int g = 0; g < GROUPS; ++g) {
#pragma unroll
        for (int r = 0; r < 4; ++r) {
            float v = maxs[g][r];
#pragma unroll
            for (int m = 1; m < 16; m <<= 1)
                v = fmaxf(v, __shfl_xor(v, m, 64));
            if (n == 0)
                part[(size_t)jc * N_ROWS + i_wave + g * 16 + q * 4 + r] = -2.f * v;
        }
    }
}

// ---------- kernel 3: fused reduce ----------
// out += [ sum_i min_c part[c][i] + sum(x^2) ] / N + sum(psi) / M
__global__ __launch_bounds__(BLOCK) void reduce_kernel(
    const float* __restrict__ part, const float* __restrict__ x,
    const float* __restrict__ psi, float* __restrict__ out) {
    const int tid = threadIdx.x;
    const int gt  = blockIdx.x * BLOCK + tid;     // [0, 32768)
    float m = part[gt];
#pragma unroll
    for (int c = 1; c < JC; ++c)
        m = fminf(m, part[(size_t)c * N_ROWS + gt]);
    float s = m;
    const float4* xv = (const float4*)x;          // N*D/4 = 524288 float4
    float x2 = 0.f;
#pragma unroll
    for (int k = 0; k < 16; ++k) {
        float4 v = xv[gt + k * 32768];
        x2 += v.x * v.x + v.y * v.y + v.z * v.z + v.w * v.w;
    }
    s = (s + x2) * (1.f / (float)N_ROWS);
    if (gt < M_COLS) s += psi[gt] * (1.f / (float)M_COLS);
    for (int off = 32; off > 0; off >>= 1) s += __shfl_down(s, off, 64);
    __shared__ float tmp[4];
    if ((tid & 63) == 0) tmp[tid >> 6] = s;
    __syncthreads();
    if (tid == 0) atomicAdd(out, tmp[0] + tmp[1] + tmp[2] + tmp[3]);
}

extern "C" void kernel_launch(void* const* d_in, const int* in_sizes, int n_in,
                              void* d_out, int out_size, void* d_ws, size_t ws_size,
                              hipStream_t stream) {
    const float* x   = (const float*)d_in[0];   // [N,D]
    const float* y   = (const float*)d_in[1];   // [M,D]
    const float* psi = (const float*)d_in[2];   // [M]
    float* out = (float*)d_out;

    // workspace layout
    float* part = (float*)d_ws;                       // JC*N floats = 2 MB
    float* th   = part + (size_t)JC * N_ROWS;         // M floats
    _Float16* yh = (_Float16*)(th + M_COLS);          // M*D halves = 1 MB (16B-aligned)

    prep_kernel<<<M_COLS / 16, BLOCK, 0, stream>>>(y, psi, yh, th, out);
    partial_min_kernel<<<dim3(N_ROWS / ROWS_PER_BLOCK, JC), BLOCK, 0, stream>>>(x, yh, th, part);
    reduce_kernel<<<N_ROWS / BLOCK, BLOCK, 0, stream>>>(part, x, psi, out);
}

// Round 10
// 103.681 us; speedup vs baseline: 1.4456x; 1.1045x over previous
//
#include <hip/hip_runtime.h>

// Problem constants (reference: N=32768, M=8192, D=64, fp32)
#define N_ROWS 32768
#define M_COLS 8192
#define D_DIM  64
#define JC     8                      // j-chunks (grid.y)
#define BLOCK  256
#define GROUPS 4                      // 16-row groups per wave -> 64 rows/wave
#define ROWS_PER_BLOCK 256            // 4 waves x 64 rows; grid.x=128 -> 4 blocks/CU
#define CHUNK  (M_COLS / JC)          // 1024 j per chunk
#define TJ     128                    // j per LDS tile (128 rows x 128 B = 16 KB)
#define NTILE  (CHUNK / TJ)           // 8 tiles per chunk

typedef _Float16 v8h __attribute__((ext_vector_type(8)));
typedef _Float16 v4h __attribute__((ext_vector_type(4)));
typedef float    v4f __attribute__((ext_vector_type(4)));

// ---------- kernel 1: yh = (half)y, th[j] = (psi[j] - ||y_j||^2)/2; zero out ----------
__global__ __launch_bounds__(BLOCK) void prep_kernel(
    const float* __restrict__ y, const float* __restrict__ psi,
    _Float16* __restrict__ yh, float* __restrict__ th, float* __restrict__ out) {
    const int tid = threadIdx.x;
    if (blockIdx.x == 0 && tid == 0) out[0] = 0.f;   // atomic accumulator init
    const int j = blockIdx.x * 16 + (tid >> 4);  // y row
    const int n = tid & 15;                      // 4-elem segment
    const float4 v = *(const float4*)(y + (size_t)j * D_DIM + n * 4);
    float s = v.x * v.x + v.y * v.y + v.z * v.z + v.w * v.w;
    v4h hv = { (_Float16)v.x, (_Float16)v.y, (_Float16)v.z, (_Float16)v.w };
    *(v4h*)(yh + (size_t)j * D_DIM + n * 4) = hv;
#pragma unroll
    for (int m = 1; m < 16; m <<= 1) s += __shfl_xor(s, m, 64);
    if (n == 0) th[j] = 0.5f * (psi[j] - s);
}

// ---------- kernel 2: MFMA partial min over a j-chunk ----------
// part[jc*N + i] = min_{j in chunk} (t[j] - 2<x_i,y_j>) = -2 max_j(<x_i,y_j>+th[j])
// R7 K-loop (block-shared double-buffered LDS, XOR-swizzled global_load_lds);
// GROUPS=4 / 128 row-blocks: same total work, 4 blocks/CU for cross-block
// overlap of the barrier drains.
__global__ __launch_bounds__(BLOCK) void partial_min_kernel(
    const float* __restrict__ x, const _Float16* __restrict__ yh,
    const float* __restrict__ th, float* __restrict__ part) {
    __shared__ __align__(16) _Float16 sY[2][TJ * D_DIM];  // 2 x 16 KB
    __shared__ __align__(16) float    sTh[2][TJ];         // 2 x 512 B

    const int tid  = threadIdx.x;
    const int lane = tid & 63, wave = tid >> 6;
    const int q = lane >> 4, n = lane & 15;
    const int jc    = blockIdx.y;
    const int jbase = jc * CHUNK;
    const int i_wave = blockIdx.x * ROWS_PER_BLOCK + wave * 64;

    // A-frags: 4 row-groups x 2 k-chunks, loaded once from fp32 x, cvt to f16.
    v8h a[GROUPS][2];
#pragma unroll
    for (int g = 0; g < GROUPS; ++g) {
        const float* px = x + (size_t)(i_wave + g * 16 + n) * D_DIM + q * 8;
#pragma unroll
        for (int c = 0; c < 2; ++c) {
            float4 f0 = *(const float4*)(px + c * 32);
            float4 f1 = *(const float4*)(px + c * 32 + 4);
            v8h av = { (_Float16)f0.x, (_Float16)f0.y, (_Float16)f0.z, (_Float16)f0.w,
                       (_Float16)f1.x, (_Float16)f1.y, (_Float16)f1.z, (_Float16)f1.w };
            a[g][c] = av;
        }
    }

    float maxs[GROUPS][4];
#pragma unroll
    for (int g = 0; g < GROUPS; ++g)
#pragma unroll
        for (int r = 0; r < 4; ++r) maxs[g][r] = -INFINITY;

    // ---- async stage of tile t into buffer b (XOR-swizzled on the GLOBAL side) ----
    // LDS 16B-slot sIdx holds (row = sIdx/8, chunk = (sIdx%8) ^ (row&7)).
    auto stage = [&](int t, int b) {
#pragma unroll
        for (int k = 0; k < 4; ++k) {
            const int sIdx = (k * 4 + wave) * 64 + lane;     // [0,1024)
            const int row  = sIdx >> 3;
            const int c    = (sIdx & 7) ^ (row & 7);
            const _Float16* g = yh + (size_t)(jbase + t * TJ + row) * D_DIM + c * 8;
            __builtin_amdgcn_global_load_lds(
                (const __attribute__((address_space(1))) void*)g,
                (__attribute__((address_space(3))) void*)(&sY[b][(size_t)(k * 4 + wave) * 512]),
                16, 0, 0);
        }
        // th tile: 128 floats = 512 B via wave 0, lanes 0-31 (lane*16B dest)
        if (wave == 0 && lane < 32) {
            const float* gt_ = th + jbase + t * TJ + lane * 4;
            __builtin_amdgcn_global_load_lds(
                (const __attribute__((address_space(1))) void*)gt_,
                (__attribute__((address_space(3))) void*)(&sTh[b][0]),
                16, 0, 0);
        }
    };

    stage(0, 0);
    __syncthreads();  // drains vmcnt(0): tile 0 resident

    const int sl0 = q ^ (n & 7);  // swizzled slot for chunk q of row (..8k+n)

    for (int t = 0; t < NTILE; ++t) {
        const int cur = t & 1;
        if (t + 1 < NTILE) stage(t + 1, cur ^ 1);  // prefetch under compute

        const _Float16* buf = &sY[cur][0];
        const float* tbuf = &sTh[cur][0];
#pragma unroll 4
        for (int ss = 0; ss < TJ / 16; ++ss) {
            // row in tile = ss*16+n (row&7 == n&7); chunk q at slot sl0, q+4 at sl0^4
            const v8h b0 = *(const v8h*)(buf + (ss * 16 + n) * 64 + sl0 * 8);
            const v8h b1 = *(const v8h*)(buf + (ss * 16 + n) * 64 + (sl0 ^ 4) * 8);
            const float tv = tbuf[ss * 16 + n];
            const v4f tv4 = { tv, tv, tv, tv };   // th[j] rides in the C operand
#pragma unroll
            for (int g = 0; g < GROUPS; ++g) {
                v4f acc = __builtin_amdgcn_mfma_f32_16x16x32_f16(a[g][0], b0, tv4, 0, 0, 0);
                acc     = __builtin_amdgcn_mfma_f32_16x16x32_f16(a[g][1], b1, acc, 0, 0, 0);
#pragma unroll
                for (int r = 0; r < 4; ++r)
                    maxs[g][r] = fmaxf(maxs[g][r], acc[r]);
            }
        }
        __syncthreads();  // all waves done reading buf `cur`; prefetch drained
    }

    // reduce max across the 16 j-phase lanes (lane bits 0..3), store -2*max
#pragma unroll
    for (int g = 0; g < GROUPS; ++g) {
#pragma unroll
        for (int r = 0; r < 4; ++r) {
            float v = maxs[g][r];
#pragma unroll
            for (int m = 1; m < 16; m <<= 1)
                v = fmaxf(v, __shfl_xor(v, m, 64));
            if (n == 0)
                part[(size_t)jc * N_ROWS + i_wave + g * 16 + q * 4 + r] = -2.f * v;
        }
    }
}

// ---------- kernel 3: fused reduce ----------
// out += [ sum_i min_c part[c][i] + sum(x^2) ] / N + sum(psi) / M
__global__ __launch_bounds__(BLOCK) void reduce_kernel(
    const float* __restrict__ part, const float* __restrict__ x,
    const float* __restrict__ psi, float* __restrict__ out) {
    const int tid = threadIdx.x;
    const int gt  = blockIdx.x * BLOCK + tid;     // [0, 32768)
    float m = part[gt];
#pragma unroll
    for (int c = 1; c < JC; ++c)
        m = fminf(m, part[(size_t)c * N_ROWS + gt]);
    float s = m;
    const float4* xv = (const float4*)x;          // N*D/4 = 524288 float4
    float x2 = 0.f;
#pragma unroll
    for (int k = 0; k < 16; ++k) {
        float4 v = xv[gt + k * 32768];
        x2 += v.x * v.x + v.y * v.y + v.z * v.z + v.w * v.w;
    }
    s = (s + x2) * (1.f / (float)N_ROWS);
    if (gt < M_COLS) s += psi[gt] * (1.f / (float)M_COLS);
    for (int off = 32; off > 0; off >>= 1) s += __shfl_down(s, off, 64);
    __shared__ float tmp[4];
    if ((tid & 63) == 0) tmp[tid >> 6] = s;
    __syncthreads();
    if (tid == 0) atomicAdd(out, tmp[0] + tmp[1] + tmp[2] + tmp[3]);
}

extern "C" void kernel_launch(void* const* d_in, const int* in_sizes, int n_in,
                              void* d_out, int out_size, void* d_ws, size_t ws_size,
                              hipStream_t stream) {
    const float* x   = (const float*)d_in[0];   // [N,D]
    const float* y   = (const float*)d_in[1];   // [M,D]
    const float* psi = (const float*)d_in[2];   // [M]
    float* out = (float*)d_out;

    // workspace layout
    float* part = (float*)d_ws;                       // JC*N floats = 1 MB
    float* th   = part + (size_t)JC * N_ROWS;         // M floats
    _Float16* yh = (_Float16*)(th + M_COLS);          // M*D halves = 1 MB (16B-aligned)

    prep_kernel<<<M_COLS / 16, BLOCK, 0, stream>>>(y, psi, yh, th, out);
    partial_min_kernel<<<dim3(N_ROWS / ROWS_PER_BLOCK, JC), BLOCK, 0, stream>>>(x, yh, th, part);
    reduce_kernel<<<N_ROWS / BLOCK, BLOCK, 0, stream>>>(part, x, psi, out);
}